// Round 7
// baseline (297.895 us; speedup 1.0000x reference)
//
#include <hip/hip_runtime.h>
#include <hip/hip_fp16.h>
#include <math.h>

// ---------------------------------------------------------------------------
// GCN 3-layer: out = sigmoid( L3(relu(L2(relu(L1(x))))) @ Wl + bl )
// hs = half((x @ W) * dinv[row]);  z = relu(dinv[d]*(hs[d]+sum hs[s])+b)
// fp32 accumulate, fp16 storage. Fused [aggregate -> MFMA matmul] per layer,
// head fused into layer-3 aggregate.
// R7: CSR partition rebuilt as deterministic two-level scan (per-chunk
// histogram matrix -> column scan -> exact offsets; ZERO global atomics in
// the scatter pass — R6's 153k contended bucketfill RMWs eliminated).
// mm1 LDS staging now packed half2 + 16B ds_write. Memset dispatch dropped.
// Aggregate FETCH floor = ~8 XCDs x table bytes (R5) — agg kernels are there.
// ---------------------------------------------------------------------------

#define BSHIFT 8
#define BNODES (1 << BSHIFT)
#define SRCBITS 17
#define MAXB 512
#define CHUNK 16384

union H8 { float4 f4; __half2 h2[4]; };

typedef _Float16 half8 __attribute__((ext_vector_type(8)));
typedef float floatx4 __attribute__((ext_vector_type(4)));

// ---- CSR pass 1: per-chunk bucket histogram -> cnt_mat[chunk][B] ----------
__global__ __launch_bounds__(256) void k_hist2(const int* __restrict__ dst, int E,
                                               int* __restrict__ cnt_mat, int B) {
    __shared__ int h[MAXB];
    int tid = threadIdx.x, c = blockIdx.x;
    h[tid] = 0; h[tid + 256] = 0;
    __syncthreads();
    int base = c * CHUNK, end = min(base + CHUNK, E);
    for (int i = base + tid; i < end; i += 256)
        atomicAdd(&h[dst[i] >> BSHIFT], 1);
    __syncthreads();
    for (int b = tid; b < B; b += 256) cnt_mat[c * B + b] = h[b];
}

// ---- CSR pass 2: column scan (one block per bucket) -----------------------
__global__ __launch_bounds__(256) void k_colscan(const int* __restrict__ cnt_mat,
                                                 int* __restrict__ rel_mat,
                                                 int* __restrict__ total,
                                                 int B, int nchunks) {
    __shared__ int s[256];
    int b = blockIdx.x, tid = threadIdx.x;
    int v = (tid < nchunks) ? cnt_mat[tid * B + b] : 0;
    s[tid] = v;
    __syncthreads();
    for (int off = 1; off < 256; off <<= 1) {
        int t = (tid >= off) ? s[tid - off] : 0;
        __syncthreads();
        s[tid] += t;
        __syncthreads();
    }
    if (tid < nchunks) rel_mat[tid * B + b] = s[tid] - v;
    if (tid == 255) total[b] = s[255];
}

// ---- CSR pass 3: exclusive scan of bucket totals --------------------------
__global__ __launch_bounds__(512) void k_bscan(const int* __restrict__ total,
                                               int* __restrict__ bucketbase,
                                               int* __restrict__ row_ptr,
                                               int B, int n, int E) {
    __shared__ int s[MAXB];
    int tid = threadIdx.x;
    int v = (tid < B) ? total[tid] : 0;
    s[tid] = v;
    __syncthreads();
    for (int off = 1; off < MAXB; off <<= 1) {
        int t = (tid >= off) ? s[tid - off] : 0;
        __syncthreads();
        s[tid] += t;
        __syncthreads();
    }
    if (tid < B) bucketbase[tid] = s[tid] - v;
    if (tid == 0) { bucketbase[B] = E; row_ptr[n] = E; }
}

// ---- CSR pass 4: partition scatter (no global atomics) --------------------
__global__ __launch_bounds__(256) void k_bucket2(const int* __restrict__ src,
                                                 const int* __restrict__ dst, int E,
                                                 const int* __restrict__ bucketbase,
                                                 const int* __restrict__ rel_mat,
                                                 unsigned int* __restrict__ edgebuf,
                                                 int B) {
    __shared__ int cur[MAXB];
    int c = blockIdx.x, tid = threadIdx.x;
    int base = c * CHUNK, end = min(base + CHUNK, E);
    for (int b = tid; b < B; b += 256) cur[b] = bucketbase[b] + rel_mat[c * B + b];
    __syncthreads();
    for (int i = base + tid; i < end; i += 256) {
        int d = dst[i];
        int b = d >> BSHIFT;
        unsigned int pk = ((unsigned int)(d & (BNODES - 1)) << SRCBITS) | (unsigned int)src[i];
        int pos = atomicAdd(&cur[b], 1);
        edgebuf[pos] = pk;
    }
}

// ---- CSR pass 5: per-bucket exact row_ptr/dinv/col ------------------------
__global__ __launch_bounds__(256) void k_build(const unsigned int* __restrict__ edgebuf,
                                               const int* __restrict__ bucketbase,
                                               int* __restrict__ row_ptr,
                                               float* __restrict__ dinv,
                                               int* __restrict__ col, int n) {
    __shared__ int cnt[BNODES];
    __shared__ int s[BNODES];
    int b = blockIdx.x;
    int tid = threadIdx.x;
    int node0 = b << BSHIFT;
    int ebase = bucketbase[b], eend = bucketbase[b + 1];
    cnt[tid] = 0;
    __syncthreads();
    for (int i = ebase + tid; i < eend; i += 256)
        atomicAdd(&cnt[edgebuf[i] >> SRCBITS], 1);
    __syncthreads();
    int c = cnt[tid];
    s[tid] = c;
    __syncthreads();
    for (int off = 1; off < 256; off <<= 1) {
        int t = (tid >= off) ? s[tid - off] : 0;
        __syncthreads();
        s[tid] += t;
        __syncthreads();
    }
    int p = ebase + s[tid] - c;
    int node = node0 + tid;
    if (node < n) { row_ptr[node] = p; dinv[node] = rsqrtf((float)(c + 1)); }
    cnt[tid] = p;
    __syncthreads();
    for (int i = ebase + tid; i < eend; i += 256) {
        unsigned int pk = edgebuf[i];
        int pos = atomicAdd(&cnt[pk >> SRCBITS], 1);
        col[pos] = (int)(pk & ((1u << SRCBITS) - 1));
    }
}

// ---- W pack (all three) into fp16 B-fragment order ------------------------
__global__ void k_packW3(const float* __restrict__ W1, const float* __restrict__ W2,
                         const float* __restrict__ W3, _Float16* __restrict__ P1,
                         _Float16* __restrict__ P2, _Float16* __restrict__ P3) {
    int e = blockIdx.x * 256 + threadIdx.x;
    const float* W; _Float16* P; int OUT, idx;
    if (e < 16384)      { W = W1; P = P1; OUT = 128; idx = e; }
    else if (e < 24576) { W = W2; P = P2; OUT = 64;  idx = e - 16384; }
    else if (e < 26624) { W = W3; P = P3; OUT = 32;  idx = e - 24576; }
    else return;
    int j = idx & 7;
    int lane = (idx >> 3) & 63;
    int rest = idx >> 9;
    int NT = OUT >> 4;
    int t = rest % NT;
    int ss = rest / NT;
    int k = ss * 32 + (lane >> 4) * 8 + j;
    int nn = t * 16 + (lane & 15);
    P[idx] = (_Float16)W[k * OUT + nn];
}

// ---- MFMA matmul (layer 1): hs = half((x@W)*dinv[row]) --------------------
template <int IN, int OUT>
__global__ __launch_bounds__(256) void k_matmul_mfma(const float* __restrict__ x,
                                                     const _Float16* __restrict__ Wpk,
                                                     const float* __restrict__ dinv,
                                                     __half* __restrict__ out, int n) {
    constexpr int S = IN / 32;
    constexpr int NT = OUT / 16;
    constexpr int LDH = IN + 8;
    __shared__ _Float16 xs[64 * LDH];

    int tid = threadIdx.x;
    int rowbase = blockIdx.x * 64;

    constexpr int TOT = 64 * IN / 8;
    const float4* x4 = (const float4*)x;
    for (int i = tid; i < TOT; i += 256) {
        int r = i / (IN / 8), kg = i % (IN / 8);
        int row = rowbase + r;
        float4 a = make_float4(0.f, 0.f, 0.f, 0.f), b = a;
        if (row < n) {
            a = x4[(size_t)row * (IN / 4) + kg * 2 + 0];
            b = x4[(size_t)row * (IN / 4) + kg * 2 + 1];
        }
        H8 u;
        u.h2[0] = __float22half2_rn(make_float2(a.x, a.y));
        u.h2[1] = __float22half2_rn(make_float2(a.z, a.w));
        u.h2[2] = __float22half2_rn(make_float2(b.x, b.y));
        u.h2[3] = __float22half2_rn(make_float2(b.z, b.w));
        *(float4*)&xs[r * LDH + kg * 8] = u.f4;
    }
    __syncthreads();

    int lane = tid & 63;
    int wave = tid >> 6;
    int m = lane & 15, quad = lane >> 4;

    floatx4 acc[NT];
#pragma unroll
    for (int t = 0; t < NT; ++t) acc[t] = (floatx4){0.f, 0.f, 0.f, 0.f};

    const half8* Wf = (const half8*)Wpk;
#pragma unroll
    for (int s = 0; s < S; ++s) {
        half8 a = *(const half8*)&xs[(wave * 16 + m) * LDH + s * 32 + quad * 8];
#pragma unroll
        for (int t = 0; t < NT; ++t) {
            half8 b = Wf[(s * NT + t) * 64 + lane];
            acc[t] = __builtin_amdgcn_mfma_f32_16x16x32_f16(a, b, acc[t], 0, 0, 0);
        }
    }

    int rbase = rowbase + wave * 16 + quad * 4;
#pragma unroll
    for (int r = 0; r < 4; ++r) {
        int row = rbase + r;
        if (row < n) {
            float dsc = dinv[row];
#pragma unroll
            for (int t = 0; t < NT; ++t)
                out[(size_t)row * OUT + t * 16 + m] = __float2half(acc[t][r] * dsc);
        }
    }
}

// ---- fused: z = relu(dinv*(agg hs)+b) in LDS, then hs' = (z@W)*dinv -------
template <int F, int OUT>
__global__ __launch_bounds__(256) void k_agg_mm(const __half* __restrict__ hs,
                                                const float* __restrict__ dinv,
                                                const float* __restrict__ bias,
                                                const int* __restrict__ row_ptr,
                                                const int* __restrict__ col,
                                                const _Float16* __restrict__ Wpk,
                                                __half* __restrict__ out, int n) {
    constexpr int S = F / 32;
    constexpr int NT = OUT / 16;
    constexpr int LDH = F + 8;
    constexpr int LPN = F / 8;
    __shared__ _Float16 zs[64 * LDH];

    int tid = threadIdx.x;
    int rowbase = blockIdx.x * 64;
    const float4* h4 = (const float4*)hs;

    for (int task = tid; task < 64 * LPN; task += 256) {
        int nl = task / LPN;
        int fg = task % LPN;
        int node = rowbase + nl;
        H8 o;
        if (node < n) {
            float acc[8];
            H8 u;
            u.f4 = h4[(size_t)node * LPN + fg];  // self loop
#pragma unroll
            for (int q = 0; q < 4; ++q) {
                float2 f = __half22float2(u.h2[q]);
                acc[2 * q + 0] = f.x;
                acc[2 * q + 1] = f.y;
            }
            int beg = row_ptr[node], end = row_ptr[node + 1];
            int j = beg;
            for (; j + 3 < end; j += 4) {
                int s0 = col[j], s1 = col[j + 1], s2 = col[j + 2], s3 = col[j + 3];
                H8 u0, u1, u2, u3;
                u0.f4 = h4[(size_t)s0 * LPN + fg];
                u1.f4 = h4[(size_t)s1 * LPN + fg];
                u2.f4 = h4[(size_t)s2 * LPN + fg];
                u3.f4 = h4[(size_t)s3 * LPN + fg];
#pragma unroll
                for (int q = 0; q < 4; ++q) {
                    float2 f0 = __half22float2(u0.h2[q]);
                    float2 f1 = __half22float2(u1.h2[q]);
                    float2 f2 = __half22float2(u2.h2[q]);
                    float2 f3 = __half22float2(u3.h2[q]);
                    acc[2 * q + 0] += (f0.x + f1.x) + (f2.x + f3.x);
                    acc[2 * q + 1] += (f0.y + f1.y) + (f2.y + f3.y);
                }
            }
            for (; j < end; ++j) {
                H8 u2;
                u2.f4 = h4[(size_t)col[j] * LPN + fg];
#pragma unroll
                for (int q = 0; q < 4; ++q) {
                    float2 f = __half22float2(u2.h2[q]);
                    acc[2 * q + 0] += f.x;
                    acc[2 * q + 1] += f.y;
                }
            }
            float dsc = dinv[node];
#pragma unroll
            for (int q = 0; q < 4; ++q) {
                float v0 = fmaxf(fmaf(acc[2 * q + 0], dsc, bias[fg * 8 + 2 * q + 0]), 0.f);
                float v1 = fmaxf(fmaf(acc[2 * q + 1], dsc, bias[fg * 8 + 2 * q + 1]), 0.f);
                o.h2[q] = __floats2half2_rn(v0, v1);
            }
        } else {
            o.f4 = make_float4(0.f, 0.f, 0.f, 0.f);
        }
        *(float4*)&zs[nl * LDH + fg * 8] = o.f4;
    }
    __syncthreads();

    int lane = tid & 63;
    int wave = tid >> 6;
    int m = lane & 15, quad = lane >> 4;

    floatx4 acc[NT];
#pragma unroll
    for (int t = 0; t < NT; ++t) acc[t] = (floatx4){0.f, 0.f, 0.f, 0.f};

    const half8* Wf = (const half8*)Wpk;
#pragma unroll
    for (int s = 0; s < S; ++s) {
        half8 a = *(const half8*)&zs[(wave * 16 + m) * LDH + s * 32 + quad * 8];
#pragma unroll
        for (int t = 0; t < NT; ++t) {
            half8 b = Wf[(s * NT + t) * 64 + lane];
            acc[t] = __builtin_amdgcn_mfma_f32_16x16x32_f16(a, b, acc[t], 0, 0, 0);
        }
    }

    int rbase = rowbase + wave * 16 + quad * 4;
#pragma unroll
    for (int r = 0; r < 4; ++r) {
        int row = rbase + r;
        if (row < n) {
            float dsc = dinv[row];
#pragma unroll
            for (int t = 0; t < NT; ++t)
                out[(size_t)row * OUT + t * 16 + m] = __float2half(acc[t][r] * dsc);
        }
    }
}

// ---- fused layer-3 aggregate + link head (F=32) ---------------------------
__global__ __launch_bounds__(256) void k_agg_final(const __half* __restrict__ hs,
                                                   const float* __restrict__ dinv,
                                                   const float* __restrict__ bias,
                                                   const int* __restrict__ row_ptr,
                                                   const int* __restrict__ col,
                                                   const float* __restrict__ Wl,
                                                   const float* __restrict__ bl,
                                                   float* __restrict__ out, int n) {
    constexpr int LPN = 4;
    int t = blockIdx.x * 256 + threadIdx.x;
    int node = t / LPN;
    int fg = t % LPN;
    if (node >= n) return;

    const float4* h4 = (const float4*)hs;
    float acc[8];
    {
        H8 u;
        u.f4 = h4[(size_t)node * LPN + fg];
#pragma unroll
        for (int q = 0; q < 4; ++q) {
            float2 f = __half22float2(u.h2[q]);
            acc[2 * q + 0] = f.x;
            acc[2 * q + 1] = f.y;
        }
    }
    int beg = row_ptr[node], end = row_ptr[node + 1];
    int j = beg;
    for (; j + 3 < end; j += 4) {
        int s0 = col[j], s1 = col[j + 1], s2 = col[j + 2], s3 = col[j + 3];
        H8 u0, u1, u2, u3;
        u0.f4 = h4[(size_t)s0 * LPN + fg];
        u1.f4 = h4[(size_t)s1 * LPN + fg];
        u2.f4 = h4[(size_t)s2 * LPN + fg];
        u3.f4 = h4[(size_t)s3 * LPN + fg];
#pragma unroll
        for (int q = 0; q < 4; ++q) {
            float2 f0 = __half22float2(u0.h2[q]);
            float2 f1 = __half22float2(u1.h2[q]);
            float2 f2 = __half22float2(u2.h2[q]);
            float2 f3 = __half22float2(u3.h2[q]);
            acc[2 * q + 0] += (f0.x + f1.x) + (f2.x + f3.x);
            acc[2 * q + 1] += (f0.y + f1.y) + (f2.y + f3.y);
        }
    }
    for (; j < end; ++j) {
        H8 u;
        u.f4 = h4[(size_t)col[j] * LPN + fg];
#pragma unroll
        for (int q = 0; q < 4; ++q) {
            float2 f = __half22float2(u.h2[q]);
            acc[2 * q + 0] += f.x;
            acc[2 * q + 1] += f.y;
        }
    }
    float dsc = dinv[node];
    float partial = 0.f;
#pragma unroll
    for (int k = 0; k < 8; ++k) {
        float v = fmaxf(fmaf(acc[k], dsc, bias[fg * 8 + k]), 0.f);
        partial = fmaf(v, Wl[fg * 8 + k], partial);
    }
    partial += __shfl_xor(partial, 1);
    partial += __shfl_xor(partial, 2);
    if (fg == 0) out[node] = 1.f / (1.f + expf(-(partial + bl[0])));
}

extern "C" void kernel_launch(void* const* d_in, const int* in_sizes, int n_in,
                              void* d_out, int out_size, void* d_ws, size_t ws_size,
                              hipStream_t stream) {
    const float* x  = (const float*)d_in[0];
    const int*   ei = (const int*)d_in[1];
    const float* W1 = (const float*)d_in[2];
    const float* b1 = (const float*)d_in[3];
    const float* W2 = (const float*)d_in[4];
    const float* b2 = (const float*)d_in[5];
    const float* W3 = (const float*)d_in[6];
    const float* b3 = (const float*)d_in[7];
    const float* Wl = (const float*)d_in[8];
    const float* bl = (const float*)d_in[9];

    const int N = in_sizes[0] / 128;
    const int E = in_sizes[1] / 2;
    const int* src = ei;
    const int* dst = ei + E;
    const int B = (N + BNODES - 1) >> BSHIFT;      // buckets (<=512)
    const int NC = (E + CHUNK - 1) / CHUNK;        // chunks  (<=256 assumed)

    char* ws = (char*)d_ws;
    size_t off = 0;
    auto take = [&](size_t bytes) -> char* {
        char* p = ws + off;
        off += (bytes + 255) & ~(size_t)255;
        return p;
    };
    int*          cnt_mat    = (int*)take((size_t)NC * B * 4);
    int*          rel_mat    = (int*)take((size_t)NC * B * 4);
    int*          total      = (int*)take(MAXB * 4);
    int*          bucketbase = (int*)take((MAXB + 1) * 4);
    unsigned int* edgebuf    = (unsigned int*)take((size_t)E * 4);
    int*          row_ptr    = (int*)take((size_t)(N + 1) * 4);
    float*        dinv       = (float*)take((size_t)N * 4);
    int*          col        = (int*)take((size_t)E * 4);
    __half*       bufA       = (__half*)take((size_t)N * 128 * 2);
    __half*       bufB       = (__half*)take((size_t)N * 128 * 2);
    _Float16*     Wpk1       = (_Float16*)take(128 * 128 * 2);
    _Float16*     Wpk2       = (_Float16*)take(128 * 64 * 2);
    _Float16*     Wpk3       = (_Float16*)take(64 * 32 * 2);
    (void)ws_size;

    int gM = (N + 63) / 64;

    // ---- CSR build: deterministic two-level scan partition ----
    k_hist2<<<NC, 256, 0, stream>>>(dst, E, cnt_mat, B);
    k_colscan<<<B, 256, 0, stream>>>(cnt_mat, rel_mat, total, B, NC);
    k_bscan<<<1, MAXB, 0, stream>>>(total, bucketbase, row_ptr, B, N, E);
    k_bucket2<<<NC, 256, 0, stream>>>(src, dst, E, bucketbase, rel_mat, edgebuf, B);
    k_build<<<B, 256, 0, stream>>>(edgebuf, bucketbase, row_ptr, dinv, col, N);

    // ---- pack weights ----
    k_packW3<<<(26624 + 255) / 256, 256, 0, stream>>>(W1, W2, W3, Wpk1, Wpk2, Wpk3);

    // ---- Layer 1 matmul: x (fp32) -> hs1 (bufA, F=128) ----
    k_matmul_mfma<128, 128><<<gM, 256, 0, stream>>>(x, Wpk1, dinv, bufA, N);

    // ---- agg1 (F=128) + mm2 (128->64): bufA -> hs2 (bufB) ----
    k_agg_mm<128, 64><<<gM, 256, 0, stream>>>(bufA, dinv, b1, row_ptr, col, Wpk2, bufB, N);

    // ---- agg2 (F=64) + mm3 (64->32): bufB -> hs3 (bufA) ----
    k_agg_mm<64, 32><<<gM, 256, 0, stream>>>(bufB, dinv, b2, row_ptr, col, Wpk3, bufA, N);

    // ---- agg3 (F=32) + link head -> out ----
    k_agg_final<<<((size_t)N * 4 + 255) / 256, 256, 0, stream>>>(
        bufA, dinv, b3, row_ptr, col, Wl, bl, (float*)d_out, N);
}